// Round 5
// baseline (504.356 us; speedup 1.0000x reference)
//
#include <hip/hip_runtime.h>

typedef __attribute__((ext_vector_type(8))) short bf16x8;
typedef __attribute__((ext_vector_type(4))) float f32x4;
typedef unsigned short us;

#define DEV static __device__ __forceinline__

// ---- config ----
constexpr int NP   = 65;      // NPATCH
constexpr int NSEQ = 512;     // B*C
constexpr int HNF  = 8320;    // DM*NP

// ---- ws layout (float offsets) ----
constexpr size_t OFF_FLAG = 0;
constexpr size_t OFF_MEAN = 16;        // 512
constexpr size_t OFF_STD  = 528;       // 512
constexpr size_t OFF_ANEG = 1040;      // 8192
constexpr size_t OFF_CONVW= 9232;      // 2048
constexpr size_t OFF_CONVB= 11280;     // 512
constexpr size_t OFF_DTPB = 11792;     // 512
constexpr size_t OFF_DD   = 12304;     // 512
constexpr size_t OFF_PEWT = 12816;     // 2048
constexpr size_t OFF_PEB  = 14864;     // 128
constexpr size_t OFF_DTW  = 14992;     // 4096
constexpr size_t OFF_INF  = 19088;     // 131072 us = 65536 f
constexpr size_t OFF_XPF  = 84624;     // 24576 us = 12288 f
constexpr size_t OFF_OPF  = 96912;     // 65536 us = 32768 f
constexpr size_t OFF_HDF  = 129680;    // 798720 us = 399360 f
constexpr size_t OFF_P    = 529040;    // 512*65*128 fp32
constexpr size_t OFF_ACT  = 4788880;   // 512*65*256 fp32
// total = 13,308,560 floats = 53.2 MB

// per-layer strides in us elements (NOT total section sizes!)
constexpr size_t STR_INF = 65536;   // 32 nt * 4 kk * 512
constexpr size_t STR_XPF = 12288;   // 3 nt * 8 kk * 512
constexpr size_t STR_OPF = 32768;   // 8 nt * 8 kk * 512

DEV float b2f(us u){ union{unsigned v; float f;} x; x.v = ((unsigned)u)<<16; return x.f; }
DEV us f2b(float f){
  union{float f32; unsigned u;} x; x.f32 = f;
  unsigned r = x.u + 0x7fffu + ((x.u>>16)&1u);
  return (us)(r>>16);
}
DEV float load_in(const void* p, size_t i, int isbf){
  return isbf ? b2f(((const us*)p)[i]) : ((const float*)p)[i];
}
DEV int detect_bf16(const void* x){
  const us* u = (const us*)x;
  int sane = 0;
  for (int i=0;i<128;i++){
    us v = u[2*i];
    int e = (v>>7)&0xff;
    if (v==0 || (e>=100 && e<=141)) sane++;
  }
  return sane >= 96;
}
DEV f32x4 mfma16(bf16x8 a, bf16x8 b, f32x4 c){
  return __builtin_amdgcn_mfma_f32_16x16x32_bf16(a,b,c,0,0,0);
}
DEV float sigm(float x){ return 1.f/(1.f+__expf(-x)); }
DEV float softplus(float x){ return fmaxf(x,0.f)+log1pf(__expf(-fabsf(x))); }

DEV void packsplit(float4 v0, float4 v1, bf16x8& hi, bf16x8& lo){
  float v[8]={v0.x,v0.y,v0.z,v0.w,v1.x,v1.y,v1.z,v1.w};
  #pragma unroll
  for (int j=0;j<8;j++){
    us h = f2b(v[j]);
    hi[j]=(short)h;
    lo[j]=(short)f2b(v[j]-b2f(h));
  }
}
// Load A-fragment chunk (8 consecutive fp32) from global, split hi/lo bf16.
DEV void loadA(const float* __restrict__ base, int K, int m, int k0,
               bf16x8& ah, bf16x8& al){
  const float* p = base + (size_t)m*K + k0;
  packsplit(*(const float4*)p, *(const float4*)(p+4), ah, al);
}

// =====================================================================
// prep
// =====================================================================
__global__ void k_prep(const void* x_enc, const void* pe_w, const void* pe_b,
                       const void* in_w, const void* conv_w, const void* conv_b,
                       const void* xp_w, const void* dtp_w, const void* dtp_b,
                       const void* A_log, const void* Dm, const void* op_w,
                       const void* head_w, float* __restrict__ ws)
{
  __shared__ int sflag;
  if (threadIdx.x==0) sflag = detect_bf16(x_enc);
  __syncthreads();
  const int isbf = sflag;
  if (blockIdx.x==0 && threadIdx.x==0) ws[OFF_FLAG] = (float)isbf;

  size_t i = (size_t)blockIdx.x*256 + threadIdx.x;
  if (i < 8192){ ws[OFF_ANEG+i] = -__expf(load_in(A_log,i,isbf)); return; } i -= 8192;
  if (i < 2048){ ws[OFF_CONVW+i] = load_in(conv_w,i,isbf); return; } i -= 2048;
  if (i < 512){ ws[OFF_CONVB+i] = load_in(conv_b,i,isbf); return; } i -= 512;
  if (i < 512){ ws[OFF_DTPB+i]  = load_in(dtp_b,i,isbf); return; } i -= 512;
  if (i < 512){ ws[OFF_DD+i]    = load_in(Dm,i,isbf); return; } i -= 512;
  if (i < 2048){ size_t k=i>>7, dm=i&127; ws[OFF_PEWT+i]=load_in(pe_w, dm*16+k, isbf); return; } i -= 2048;
  if (i < 128){ ws[OFF_PEB+i]   = load_in(pe_b,i,isbf); return; } i -= 128;
  if (i < 4096){ ws[OFF_DTW+i]  = load_in(dtp_w,i,isbf); return; } i -= 4096;
  if (i < 16384){ // INF: [l][nt32][kk4][lane][8]; B[k=d(128)][e(512)]=in_w[e][k]
    size_t lane=i&63, tile=i>>6;
    size_t kk=tile&3, nt=(tile>>2)&31, l=tile>>7;
    size_t e=nt*16+(lane&15), k0=kk*32+((lane>>4)*8);
    bf16x8 v;
    #pragma unroll
    for (int j=0;j<8;j++) v[j]=(short)f2b(load_in(in_w,(l*512+e)*128+k0+j,isbf));
    *(bf16x8*)&((us*)(ws+OFF_INF))[i*8] = v; return;
  } i -= 16384;
  if (i < 3072){ // XPF: [l][nt3][kk8]; B[k=d(256)][o(48 pad)]=xp_w[o][k]
    size_t lane=i&63, tile=i>>6;
    size_t kk=tile&7, rest=tile>>3, nt=rest%3, l=rest/3;
    size_t o=nt*16+(lane&15), k0=kk*32+((lane>>4)*8);
    bf16x8 v;
    #pragma unroll
    for (int j=0;j<8;j++) v[j]=(short)((o<40)? f2b(load_in(xp_w,(l*40+o)*256+k0+j,isbf)) : 0);
    *(bf16x8*)&((us*)(ws+OFF_XPF))[i*8] = v; return;
  } i -= 3072;
  if (i < 8192){ // OPF: [l][nt8][kk8]; B[k=d(256)][dm(128)]=op_w[dm][k]
    size_t lane=i&63, tile=i>>6;
    size_t kk=tile&7, nt=(tile>>3)&7, l=tile>>6;
    size_t dm=nt*16+(lane&15), k0=kk*32+((lane>>4)*8);
    bf16x8 v;
    #pragma unroll
    for (int j=0;j<8;j++) v[j]=(short)f2b(load_in(op_w,(l*128+dm)*256+k0+j,isbf));
    *(bf16x8*)&((us*)(ws+OFF_OPF))[i*8] = v; return;
  } i -= 8192;
  if (i < 99840){ // HDF: [nt6][kk260]; B[k(8320)][pred(96)]=head_w[pred][k]
    size_t lane=i&63, tile=i>>6;
    size_t kk=tile%260, nt=tile/260;
    size_t pr=nt*16+(lane&15), k0=kk*32+((lane>>4)*8);
    bf16x8 v;
    #pragma unroll
    for (int j=0;j<8;j++) v[j]=(short)f2b(load_in(head_w,pr*8320+k0+j,isbf));
    *(bf16x8*)&((us*)(ws+OFF_HDF))[i*8] = v; return;
  }
}

// =====================================================================
// RevIN + patch-embed -> P fp32
// =====================================================================
__global__ void k_embed(const void* __restrict__ x_enc, float* __restrict__ ws)
{
  const int n = blockIdx.x, tid = threadIdx.x;
  const int b = n>>4, c = n&15;
  const int isbf = ws[OFF_FLAG] != 0.f;
  __shared__ __align__(16) float sx[512];
  __shared__ __align__(16) float spe[16*128];
  __shared__ __align__(16) float spb[128];
  __shared__ float rs[4], rq[4], sm[2];

  float v0 = load_in(x_enc, ((size_t)b*512+tid)*16 + c, isbf);
  float v1 = load_in(x_enc, ((size_t)b*512+tid+256)*16 + c, isbf);
  float s = v0+v1, q = v0*v0+v1*v1;
  for (int o=32;o;o>>=1){ s += __shfl_down(s,o,64); q += __shfl_down(q,o,64); }
  const int w = tid>>6, lane = tid&63;
  if (lane==0){ rs[w]=s; rq[w]=q; }
  __syncthreads();
  if (tid==0){
    float S=rs[0]+rs[1]+rs[2]+rs[3], Q=rq[0]+rq[1]+rq[2]+rq[3];
    float mean = S*(1.f/512.f);
    float var = fmaxf(Q*(1.f/512.f)-mean*mean, 0.f);
    float sd = sqrtf(var+1e-5f);
    sm[0]=mean; sm[1]=1.f/sd;
    ws[OFF_MEAN+n]=mean; ws[OFF_STD+n]=sd;
  }
  __syncthreads();
  const float mean=sm[0], rstd=sm[1];
  sx[tid]=(v0-mean)*rstd; sx[tid+256]=(v1-mean)*rstd;
  for (int i=tid;i<2048;i+=256) spe[i]=ws[OFF_PEWT+i];
  if (tid<128) spb[tid]=ws[OFF_PEB+tid];
  __syncthreads();

  float* P = ws + OFF_P + (size_t)n*HNF;
  for (int i=tid;i<NP*128;i+=256){
    int t=i>>7, dm=i&127;
    float acc = spb[dm];
    int j0 = t*8-8;
    #pragma unroll
    for (int k=0;k<16;k++){ int j=j0+k; if ((unsigned)j<512u) acc += sx[j]*spe[k*128+dm]; }
    P[i] = acc;
  }
}

// =====================================================================
// in_proj xin-half: A=P[65x128] (direct global frags), B=INF nt0..15 -> ACT
// =====================================================================
__global__ __launch_bounds__(256,3)
void k_inproj(int l, float* __restrict__ ws)
{
  const int n = blockIdx.x, tid = threadIdx.x;
  const int w = tid>>6, lane = tid&63, ml = lane&15, quad = lane>>4;
  const float* P = ws + OFF_P + (size_t)n*HNF;
  const us* INF = (const us*)(ws+OFF_INF) + (size_t)l*STR_INF;

  f32x4 acc[5][4];
  #pragma unroll
  for (int mt=0;mt<5;mt++)
    #pragma unroll
    for (int p=0;p<4;p++){ f32x4 z={0,0,0,0}; acc[mt][p]=z; }

  #pragma unroll
  for (int kk=0;kk<4;kk++){
    bf16x8 B[4];
    #pragma unroll
    for (int p=0;p<4;p++) B[p] = *(const bf16x8*)&INF[(((size_t)(w*4+p)*4+kk))*512 + lane*8];
    #pragma unroll
    for (int mt=0;mt<5;mt++){
      int m = mt*16+ml; if (m>64) m=64;
      bf16x8 ah,al; loadA(P,128,m,kk*32+quad*8,ah,al);
      #pragma unroll
      for (int p=0;p<4;p++) acc[mt][p] = mfma16(ah,B[p],mfma16(al,B[p],acc[mt][p]));
    }
  }
  float* act = ws + OFF_ACT + (size_t)n*NP*256;
  #pragma unroll
  for (int p=0;p<4;p++){
    int e = (w*4+p)*16+ml;
    #pragma unroll
    for (int mt=0;mt<5;mt++)
      #pragma unroll
      for (int r=0;r<4;r++){
        int t = mt*16+quad*4+r;
        if (t<NP) act[(size_t)t*256+e] = acc[mt][p][r];
      }
  }
}

// =====================================================================
// conv+silu (t-split 2) -> x_proj (direct global frags) -> scan (split 2)
// block = one seq, 512 threads.
// =====================================================================
__global__ __launch_bounds__(512,4)
void k_convscan(int l, float* __restrict__ ws)
{
  const int n = blockIdx.x, tid = threadIdx.x;
  __shared__ __align__(16) float s_dbc[NP*52];
  float* act = ws + OFF_ACT + (size_t)n*NP*256;

  // ---- conv + SiLU, in place, t-split halves with pre-barrier warmup ----
  {
    const int d = tid&255, half = tid>>8;
    float x0=0.f,x1=0.f,x2=0.f;
    if (half){ x0=act[30*256+d]; x1=act[31*256+d]; x2=act[32*256+d]; }
    __syncthreads();
    const float4 wv = ((const float4*)(ws+OFF_CONVW))[l*256+d];
    const float bb = ws[OFF_CONVB + l*256+d];
    const int t0 = half?33:0, tn = half?NP:33;
    for (int t=t0;t<tn;t++){
      float xi = act[(size_t)t*256+d];
      float v = bb + wv.x*x0 + wv.y*x1 + wv.z*x2 + wv.w*xi;
      x0=x1; x1=x2; x2=xi;
      act[(size_t)t*256+d] = v * sigm(v);
    }
  }
  __threadfence_block();
  __syncthreads();

  // ---- x_proj: 15 tiles over 8 waves, A-frags direct from act ----
  const int w = tid>>6, lane = tid&63, ml = lane&15, quad = lane>>4;
  const us* XPF = (const us*)(ws+OFF_XPF) + (size_t)l*STR_XPF;
  for (int ti=w; ti<15; ti+=8){
    int mt=ti/3, nt=ti%3;
    int m = mt*16+ml; if (m>64) m=64;
    f32x4 acc={0,0,0,0};
    #pragma unroll
    for (int kk=0;kk<8;kk++){
      bf16x8 ah,al; loadA(act,256,m,kk*32+quad*8,ah,al);
      bf16x8 b = *(const bf16x8*)&XPF[((size_t)(nt*8+kk))*512 + lane*8];
      acc = mfma16(ah,b,mfma16(al,b,acc));
    }
    int o = nt*16+ml;
    #pragma unroll
    for (int r=0;r<4;r++){
      int t = mt*16+quad*4+r;
      if (t<NP && o<48) s_dbc[t*52+o] = acc[r];
    }
  }
  __syncthreads();

  // ---- scan: thread=(d, s-half of 8 states) ----
  {
    const int d = tid>>1, sh = tid&1, s0 = sh*8;
    float A_[8], wdt[8];
    {
      const float* ap = ws+OFF_ANEG + ((size_t)l*256+d)*16 + s0;
      const float* wp = ws+OFF_DTW + ((size_t)l*256+d)*8;
      #pragma unroll
      for (int j2=0;j2<8;j2++){ A_[j2]=ap[j2]; wdt[j2]=wp[j2]; }
    }
    const float Dv = ws[OFF_DD + l*256+d];
    const float bias = ws[OFF_DTPB + l*256+d];
    float h[8];
    #pragma unroll
    for (int ss=0;ss<8;ss++) h[ss]=0.f;
    for (int t=0;t<NP;t++){
      const float* row = &s_dbc[t*52];
      float4 a0=*(const float4*)(row), a1=*(const float4*)(row+4);
      float din = bias + a0.x*wdt[0]+a0.y*wdt[1]+a0.z*wdt[2]+a0.w*wdt[3]
                       + a1.x*wdt[4]+a1.y*wdt[5]+a1.z*wdt[6]+a1.w*wdt[7];
      float dtv = softplus(din);
      float xv = act[(size_t)t*256+d];
      float dtx = dtv*xv;
      float4 B0=*(const float4*)(row+8+s0),  B1=*(const float4*)(row+12+s0);
      float4 C0=*(const float4*)(row+24+s0), C1=*(const float4*)(row+28+s0);
      float Bv[8]={B0.x,B0.y,B0.z,B0.w,B1.x,B1.y,B1.z,B1.w};
      float Cv[8]={C0.x,C0.y,C0.z,C0.w,C1.x,C1.y,C1.z,C1.w};
      float y = 0.f;
      #pragma unroll
      for (int ss=0;ss<8;ss++){
        float dA = __expf(dtv*A_[ss]);
        h[ss] = dA*h[ss] + dtx*Bv[ss];
        y += h[ss]*Cv[ss];
      }
      y += __shfl_xor(y,1,64);
      if (sh==0) act[(size_t)t*256+d] = y + xv*Dv;
    }
  }
}

// =====================================================================
// z-half GEMM (recompute from P, direct frags) + silu-gating in place
// =====================================================================
__global__ __launch_bounds__(256,3)
void k_zgate(int l, float* __restrict__ ws)
{
  const int n = blockIdx.x, tid = threadIdx.x;
  const int w = tid>>6, lane = tid&63, ml = lane&15, quad = lane>>4;
  const float* P = ws + OFF_P + (size_t)n*HNF;
  const us* INF = (const us*)(ws+OFF_INF) + (size_t)l*STR_INF;

  f32x4 acc[5][4];
  #pragma unroll
  for (int mt=0;mt<5;mt++)
    #pragma unroll
    for (int p=0;p<4;p++){ f32x4 z={0,0,0,0}; acc[mt][p]=z; }

  #pragma unroll
  for (int kk=0;kk<4;kk++){
    bf16x8 B[4];
    #pragma unroll
    for (int p=0;p<4;p++) B[p] = *(const bf16x8*)&INF[(((size_t)(16+w*4+p)*4+kk))*512 + lane*8];
    #pragma unroll
    for (int mt=0;mt<5;mt++){
      int m = mt*16+ml; if (m>64) m=64;
      bf16x8 ah,al; loadA(P,128,m,kk*32+quad*8,ah,al);
      #pragma unroll
      for (int p=0;p<4;p++) acc[mt][p] = mfma16(ah,B[p],mfma16(al,B[p],acc[mt][p]));
    }
  }
  float* act = ws + OFF_ACT + (size_t)n*NP*256;
  #pragma unroll
  for (int p=0;p<4;p++){
    int d = (w*4+p)*16+ml;
    #pragma unroll
    for (int mt=0;mt<5;mt++)
      #pragma unroll
      for (int r=0;r<4;r++){
        int t = mt*16+quad*4+r;
        if (t<NP){
          float zv = acc[mt][p][r];
          float g0 = act[(size_t)t*256+d];
          act[(size_t)t*256+d] = g0 * zv * sigm(zv);
        }
      }
  }
}

// =====================================================================
// out_proj: A=g[65x256] (direct frags), B=OPF -> P fp32
// =====================================================================
__global__ __launch_bounds__(256,4)
void k_outproj(int l, float* __restrict__ ws)
{
  const int n = blockIdx.x, tid = threadIdx.x;
  const int w = tid>>6, lane = tid&63, ml = lane&15, quad = lane>>4;
  const float* act = ws + OFF_ACT + (size_t)n*NP*256;
  const us* OPF = (const us*)(ws+OFF_OPF) + (size_t)l*STR_OPF;

  f32x4 acc[5][2];
  #pragma unroll
  for (int mt=0;mt<5;mt++)
    #pragma unroll
    for (int p=0;p<2;p++){ f32x4 z={0,0,0,0}; acc[mt][p]=z; }

  #pragma unroll
  for (int kk=0;kk<8;kk++){
    bf16x8 B[2];
    #pragma unroll
    for (int p=0;p<2;p++) B[p] = *(const bf16x8*)&OPF[(((size_t)(w*2+p)*8+kk))*512 + lane*8];
    #pragma unroll
    for (int mt=0;mt<5;mt++){
      int m = mt*16+ml; if (m>64) m=64;
      bf16x8 ah,al; loadA(act,256,m,kk*32+quad*8,ah,al);
      #pragma unroll
      for (int p=0;p<2;p++) acc[mt][p] = mfma16(ah,B[p],mfma16(al,B[p],acc[mt][p]));
    }
  }
  float* P = ws + OFF_P + (size_t)n*HNF;
  #pragma unroll
  for (int p=0;p<2;p++){
    int dm = (w*2+p)*16+ml;
    #pragma unroll
    for (int mt=0;mt<5;mt++)
      #pragma unroll
      for (int r=0;r<4;r++){
        int t = mt*16+quad*4+r;
        if (t<NP) P[(size_t)t*128+dm] = acc[mt][p][r];
      }
  }
}

// =====================================================================
// head GEMM (M=512,N=96,K=8320) + de-norm; 8 waves split K.
// =====================================================================
__global__ __launch_bounds__(512)
void k_head(const float* __restrict__ ws, void* __restrict__ out)
{
  const int blk = blockIdx.x;
  const int nt = blk%6, mt = blk/6;
  const int tid = threadIdx.x, w = tid>>6, lane = tid&63, ml = lane&15, quad = lane>>4;
  const float* P = ws + OFF_P;
  const us* HDF = (const us*)(ws+OFF_HDF);
  __shared__ __align__(16) float red[8][64][4];

  const int base = w*32 + (w<4? w:4);
  const int cnt  = 32 + (w<4? 1:0);
  f32x4 acc={0,0,0,0};
  const float* arow = P + (size_t)(mt*16+ml)*HNF + quad*8;
  for (int i=0;i<cnt;i++){
    int kk = base+i;
    const float* ap = arow + (size_t)kk*32;
    bf16x8 ah,al; packsplit(*(const float4*)ap, *(const float4*)(ap+4), ah, al);
    bf16x8 b = *(const bf16x8*)&HDF[((size_t)(nt*260+kk))*512 + lane*8];
    acc = mfma16(ah,b,mfma16(al,b,acc));
  }
  #pragma unroll
  for (int r=0;r<4;r++) red[w][lane][r]=acc[r];
  __syncthreads();
  if (w==0){
    const int isbf = ws[OFF_FLAG]!=0.f;
    #pragma unroll
    for (int r=0;r<4;r++){
      float s = 0.f;
      #pragma unroll
      for (int ww=0;ww<8;ww++) s += red[ww][lane][r];
      int nseq = mt*16 + quad*4 + r;
      int pred = nt*16 + ml;
      float val = s*ws[OFF_STD+nseq] + ws[OFF_MEAN+nseq];
      size_t o = ((size_t)(nseq>>4)*96 + pred)*16 + (nseq&15);
      if (isbf) ((us*)out)[o] = f2b(val);
      else      ((float*)out)[o] = val;
    }
  }
}

extern "C" void kernel_launch(void* const* d_in, const int* in_sizes, int n_in,
                              void* d_out, int out_size, void* d_ws, size_t ws_size,
                              hipStream_t stream)
{
  (void)in_sizes; (void)n_in; (void)out_size; (void)ws_size;
  float* ws = (float*)d_ws;
  const void* x_enc = d_in[0];
  const void* pe_w  = d_in[2];  const void* pe_b  = d_in[3];
  const void* in_w  = d_in[4];  const void* conv_w= d_in[5];
  const void* conv_b= d_in[6];  const void* xp_w  = d_in[7];
  const void* dtp_w = d_in[8];  const void* dtp_b = d_in[9];
  const void* A_log = d_in[10]; const void* Dm    = d_in[11];
  const void* op_w  = d_in[12]; const void* head_w= d_in[13];

  k_prep<<<569,256,0,stream>>>(x_enc,pe_w,pe_b,in_w,conv_w,conv_b,xp_w,dtp_w,
                               dtp_b,A_log,Dm,op_w,head_w,ws);
  k_embed<<<NSEQ,256,0,stream>>>(x_enc,ws);
  for (int l=0;l<2;l++){
    k_inproj  <<<NSEQ,256,0,stream>>>(l,ws);
    k_convscan<<<NSEQ,512,0,stream>>>(l,ws);
    k_zgate   <<<NSEQ,256,0,stream>>>(l,ws);
    k_outproj <<<NSEQ,256,0,stream>>>(l,ws);
  }
  k_head<<<192,512,0,stream>>>(ws,d_out);
}

// Round 6
// 424.134 us; speedup vs baseline: 1.1891x; 1.1891x over previous
//
#include <hip/hip_runtime.h>

typedef __attribute__((ext_vector_type(8))) short bf16x8;
typedef __attribute__((ext_vector_type(4))) float f32x4;
typedef unsigned short us;

#define DEV static __device__ __forceinline__

// ---- config ----
constexpr int NP   = 65;      // NPATCH
constexpr int NSEQ = 512;     // B*C
constexpr int HNF  = 8320;    // DM*NP
constexpr int LOPL = NSEQ*HNF;   // shorts between hi and lo planes

// ---- ws layout (float offsets) ----
constexpr size_t OFF_FLAG = 0;
constexpr size_t OFF_MEAN = 16;        // 512
constexpr size_t OFF_STD  = 528;       // 512
constexpr size_t OFF_ANEG = 1040;      // 8192
constexpr size_t OFF_CONVW= 9232;      // 2048
constexpr size_t OFF_CONVB= 11280;     // 512
constexpr size_t OFF_DTPB = 11792;     // 512
constexpr size_t OFF_DD   = 12304;     // 512
constexpr size_t OFF_PEWT = 12816;     // 2048
constexpr size_t OFF_PEB  = 14864;     // 128
constexpr size_t OFF_DTW  = 14992;     // 4096
constexpr size_t OFF_INF  = 19088;     // 131072 us = 65536 f
constexpr size_t OFF_XPF  = 84624;     // 24576 us = 12288 f
constexpr size_t OFF_OPF  = 96912;     // 65536 us = 32768 f
constexpr size_t OFF_HDF  = 129680;    // 798720 us = 399360 f
constexpr size_t OFF_PA   = 529040;    // hi+lo planes: 2*NSEQ*HNF shorts = NSEQ*HNF f
constexpr size_t OFF_PB   = OFF_PA + (size_t)NSEQ*HNF;   // 4788880
// total = OFF_PB + NSEQ*HNF = 9,048,720 floats = 36.2 MB

// per-layer strides in us elements (NOT total section sizes!)
constexpr size_t STR_INF = 65536;   // 32 nt * 4 kk * 512
constexpr size_t STR_XPF = 12288;   // 3 nt * 8 kk * 512
constexpr size_t STR_OPF = 32768;   // 8 nt * 8 kk * 512

DEV float b2f(us u){ union{unsigned v; float f;} x; x.v = ((unsigned)u)<<16; return x.f; }
DEV us f2b(float f){
  union{float f32; unsigned u;} x; x.f32 = f;
  unsigned r = x.u + 0x7fffu + ((x.u>>16)&1u);
  return (us)(r>>16);
}
DEV void split2(float v, us& h, us& l){ h = f2b(v); l = f2b(v - b2f(h)); }
DEV float load_in(const void* p, size_t i, int isbf){
  return isbf ? b2f(((const us*)p)[i]) : ((const float*)p)[i];
}
DEV int detect_bf16(const void* x){
  const us* u = (const us*)x;
  int sane = 0;
  for (int i=0;i<128;i++){
    us v = u[2*i];
    int e = (v>>7)&0xff;
    if (v==0 || (e>=100 && e<=141)) sane++;
  }
  return sane >= 96;
}
DEV f32x4 mfma16(bf16x8 a, bf16x8 b, f32x4 c){
  return __builtin_amdgcn_mfma_f32_16x16x32_bf16(a,b,c,0,0,0);
}
DEV float sigm(float x){ return 1.f/(1.f+__expf(-x)); }
DEV float softplus(float x){ return fmaxf(x,0.f)+log1pf(__expf(-fabsf(x))); }

// =====================================================================
// prep (round-2/5 proven layouts)
// =====================================================================
__global__ void k_prep(const void* x_enc, const void* pe_w, const void* pe_b,
                       const void* in_w, const void* conv_w, const void* conv_b,
                       const void* xp_w, const void* dtp_w, const void* dtp_b,
                       const void* A_log, const void* Dm, const void* op_w,
                       const void* head_w, float* __restrict__ ws)
{
  __shared__ int sflag;
  if (threadIdx.x==0) sflag = detect_bf16(x_enc);
  __syncthreads();
  const int isbf = sflag;
  if (blockIdx.x==0 && threadIdx.x==0) ws[OFF_FLAG] = (float)isbf;

  size_t i = (size_t)blockIdx.x*256 + threadIdx.x;
  if (i < 8192){ ws[OFF_ANEG+i] = -__expf(load_in(A_log,i,isbf)); return; } i -= 8192;
  if (i < 2048){ ws[OFF_CONVW+i] = load_in(conv_w,i,isbf); return; } i -= 2048;
  if (i < 512){ ws[OFF_CONVB+i] = load_in(conv_b,i,isbf); return; } i -= 512;
  if (i < 512){ ws[OFF_DTPB+i]  = load_in(dtp_b,i,isbf); return; } i -= 512;
  if (i < 512){ ws[OFF_DD+i]    = load_in(Dm,i,isbf); return; } i -= 512;
  if (i < 2048){ size_t k=i>>7, dm=i&127; ws[OFF_PEWT+i]=load_in(pe_w, dm*16+k, isbf); return; } i -= 2048;
  if (i < 128){ ws[OFF_PEB+i]   = load_in(pe_b,i,isbf); return; } i -= 128;
  if (i < 4096){ ws[OFF_DTW+i]  = load_in(dtp_w,i,isbf); return; } i -= 4096;
  if (i < 16384){ // INF: [l][nt32][kk4][lane][8]; B[k=d(128)][e(512)]=in_w[e][k]
    size_t lane=i&63, tile=i>>6;
    size_t kk=tile&3, nt=(tile>>2)&31, l=tile>>7;
    size_t e=nt*16+(lane&15), k0=kk*32+((lane>>4)*8);
    bf16x8 v;
    #pragma unroll
    for (int j=0;j<8;j++) v[j]=(short)f2b(load_in(in_w,(l*512+e)*128+k0+j,isbf));
    *(bf16x8*)&((us*)(ws+OFF_INF))[i*8] = v; return;
  } i -= 16384;
  if (i < 3072){ // XPF: [l][nt3][kk8]; B[k=d(256)][o(48 pad)]=xp_w[o][k]
    size_t lane=i&63, tile=i>>6;
    size_t kk=tile&7, rest=tile>>3, nt=rest%3, l=rest/3;
    size_t o=nt*16+(lane&15), k0=kk*32+((lane>>4)*8);
    bf16x8 v;
    #pragma unroll
    for (int j=0;j<8;j++) v[j]=(short)((o<40)? f2b(load_in(xp_w,(l*40+o)*256+k0+j,isbf)) : 0);
    *(bf16x8*)&((us*)(ws+OFF_XPF))[i*8] = v; return;
  } i -= 3072;
  if (i < 8192){ // OPF: [l][nt8][kk8]; B[k=d(256)][dm(128)]=op_w[dm][k]
    size_t lane=i&63, tile=i>>6;
    size_t kk=tile&7, nt=(tile>>3)&7, l=tile>>6;
    size_t dm=nt*16+(lane&15), k0=kk*32+((lane>>4)*8);
    bf16x8 v;
    #pragma unroll
    for (int j=0;j<8;j++) v[j]=(short)f2b(load_in(op_w,(l*128+dm)*256+k0+j,isbf));
    *(bf16x8*)&((us*)(ws+OFF_OPF))[i*8] = v; return;
  } i -= 8192;
  if (i < 99840){ // HDF: [nt6][kk260]; B[k(8320)][pred(96)]=head_w[pred][k]
    size_t lane=i&63, tile=i>>6;
    size_t kk=tile%260, nt=tile/260;
    size_t pr=nt*16+(lane&15), k0=kk*32+((lane>>4)*8);
    bf16x8 v;
    #pragma unroll
    for (int j=0;j<8;j++) v[j]=(short)f2b(load_in(head_w,pr*8320+k0+j,isbf));
    *(bf16x8*)&((us*)(ws+OFF_HDF))[i*8] = v; return;
  }
}

// =====================================================================
// RevIN + patch-embed -> PA (hi/lo bf16 planes)
// =====================================================================
__global__ void k_embed(const void* __restrict__ x_enc, float* __restrict__ ws)
{
  const int n = blockIdx.x, tid = threadIdx.x;
  const int b = n>>4, c = n&15;
  const int isbf = ws[OFF_FLAG] != 0.f;
  __shared__ __align__(16) float sx[512];
  __shared__ __align__(16) float spe[16*128];
  __shared__ __align__(16) float spb[128];
  __shared__ float rs[4], rq[4], sm[2];

  float v0 = load_in(x_enc, ((size_t)b*512+tid)*16 + c, isbf);
  float v1 = load_in(x_enc, ((size_t)b*512+tid+256)*16 + c, isbf);
  float s = v0+v1, q = v0*v0+v1*v1;
  for (int o=32;o;o>>=1){ s += __shfl_down(s,o,64); q += __shfl_down(q,o,64); }
  const int w = tid>>6, lane = tid&63;
  if (lane==0){ rs[w]=s; rq[w]=q; }
  __syncthreads();
  if (tid==0){
    float S=rs[0]+rs[1]+rs[2]+rs[3], Q=rq[0]+rq[1]+rq[2]+rq[3];
    float mean = S*(1.f/512.f);
    float var = fmaxf(Q*(1.f/512.f)-mean*mean, 0.f);
    float sd = sqrtf(var+1e-5f);
    sm[0]=mean; sm[1]=1.f/sd;
    ws[OFF_MEAN+n]=mean; ws[OFF_STD+n]=sd;
  }
  __syncthreads();
  const float mean=sm[0], rstd=sm[1];
  sx[tid]=(v0-mean)*rstd; sx[tid+256]=(v1-mean)*rstd;
  for (int i=tid;i<2048;i+=256) spe[i]=ws[OFF_PEWT+i];
  if (tid<128) spb[tid]=ws[OFF_PEB+tid];
  __syncthreads();

  us* pa_hi = (us*)(ws+OFF_PA);
  us* pa_lo = pa_hi + LOPL;
  for (int i=tid;i<NP*128;i+=256){
    int t=i>>7, dm=i&127;
    float acc = spb[dm];
    int j0 = t*8-8;
    #pragma unroll
    for (int k=0;k<16;k++){ int j=j0+k; if ((unsigned)j<512u) acc += sx[j]*spe[k*128+dm]; }
    us h,lo2; split2(acc,h,lo2);
    pa_hi[(size_t)n*HNF+i] = h;
    pa_lo[(size_t)n*HNF+i] = lo2;
  }
}

// =====================================================================
// Fused Mamba layer: 512 threads, 79040 B LDS (2 blocks/CU, 16 waves/CU)
// =====================================================================
__global__ __launch_bounds__(512,4)
void k_layer(int l, const us* __restrict__ pin, us* __restrict__ pout,
             float* __restrict__ ws)
{
  const int n = blockIdx.x, tid = threadIdx.x;
  const int w = tid>>6, lane = tid&63, ml = lane&15, quad = lane>>4;

  // LDS: s_hi[65][264] bf16 | s_lo[65][264] bf16 | s_dt[65][8] f32 | s_bc[65][32] f32
  __shared__ __align__(16) unsigned char arena[79040];
  us* s_hi = (us*)arena;
  us* s_lo = (us*)(arena+34320);
  float* s_dt = (float*)(arena+68640);
  float* s_bc = (float*)(arena+70720);

  const us* INF = (const us*)(ws+OFF_INF) + (size_t)l*STR_INF;
  const us* XPF = (const us*)(ws+OFF_XPF) + (size_t)l*STR_XPF;
  const us* OPF = (const us*)(ws+OFF_OPF) + (size_t)l*STR_OPF;
  const us* phi = pin + (size_t)n*HNF;
  const us* plo = phi + LOPL;

  // ---- phase 1: in_proj xin-half (nt = 2w, 2w+1), A = p planes (global) ----
  {
    f32x4 acc[5][2];
    #pragma unroll
    for (int mt=0;mt<5;mt++){
      #pragma unroll
      for (int p=0;p<2;p++){ f32x4 z={0,0,0,0}; acc[mt][p]=z; }
    }
    #pragma unroll
    for (int kk=0;kk<4;kk++){
      bf16x8 B0 = *(const bf16x8*)&INF[((size_t)((2*w+0)*4+kk))*512 + lane*8];
      bf16x8 B1 = *(const bf16x8*)&INF[((size_t)((2*w+1)*4+kk))*512 + lane*8];
      #pragma unroll
      for (int mt=0;mt<5;mt++){
        int m = mt*16+ml; if (m>64) m=64;
        bf16x8 ah = *(const bf16x8*)&phi[(size_t)m*128 + kk*32 + quad*8];
        bf16x8 al = *(const bf16x8*)&plo[(size_t)m*128 + kk*32 + quad*8];
        acc[mt][0] = mfma16(ah,B0,mfma16(al,B0,acc[mt][0]));
        acc[mt][1] = mfma16(ah,B1,mfma16(al,B1,acc[mt][1]));
      }
    }
    #pragma unroll
    for (int p=0;p<2;p++){
      int e = (2*w+p)*16+ml;
      #pragma unroll
      for (int mt=0;mt<5;mt++)
        #pragma unroll
        for (int r=0;r<4;r++){
          int t = mt*16+quad*4+r;
          if (t<NP){
            us h,lo2; split2(acc[mt][p][r],h,lo2);
            s_hi[t*264+e]=h; s_lo[t*264+e]=lo2;
          }
        }
    }
  }
  __syncthreads();

  // ---- phase 2: causal conv(4)+SiLU in place, t-split halves ----
  {
    const int d = tid&255, half = tid>>8;
    float x0=0.f,x1=0.f,x2=0.f;
    if (half){
      x0 = b2f(s_hi[30*264+d])+b2f(s_lo[30*264+d]);
      x1 = b2f(s_hi[31*264+d])+b2f(s_lo[31*264+d]);
      x2 = b2f(s_hi[32*264+d])+b2f(s_lo[32*264+d]);
    }
    __syncthreads();
    const float4 wv = ((const float4*)(ws+OFF_CONVW))[l*256+d];
    const float bb = ws[OFF_CONVB + l*256+d];
    const int t0 = half?33:0, tn = half?NP:33;
    for (int t=t0;t<tn;t++){
      float xi = b2f(s_hi[t*264+d])+b2f(s_lo[t*264+d]);
      float v = bb + wv.x*x0 + wv.y*x1 + wv.z*x2 + wv.w*xi;
      x0=x1; x1=x2; x2=xi;
      float sv = v * sigm(v);
      us h,lo2; split2(sv,h,lo2);
      s_hi[t*264+d]=h; s_lo[t*264+d]=lo2;
    }
  }
  __syncthreads();

  // ---- phase 3: x_proj (15 tiles / 8 waves), A = s_hi/s_lo ----
  {
    for (int ti=w; ti<15; ti+=8){
      int mt=ti/3, nt=ti%3;
      int row = mt*16+ml; if (row>64) row=64;
      f32x4 acc={0,0,0,0};
      #pragma unroll
      for (int kk=0;kk<8;kk++){
        bf16x8 ah = *(const bf16x8*)&s_hi[row*264 + kk*32 + quad*8];
        bf16x8 al = *(const bf16x8*)&s_lo[row*264 + kk*32 + quad*8];
        bf16x8 b  = *(const bf16x8*)&XPF[((size_t)(nt*8+kk))*512 + lane*8];
        acc = mfma16(ah,b,mfma16(al,b,acc));
      }
      int o = nt*16+ml;
      #pragma unroll
      for (int r=0;r<4;r++){
        int t = mt*16+quad*4+r;
        if (t<NP && o<40){
          if (o<8) s_dt[t*8+o] = acc[r];
          else     s_bc[t*32+(o-8)] = acc[r];
        }
      }
    }
  }
  __syncthreads();

  // ---- phase 4: scan, thread=(d, s-half of 8 states); g0 -> s_hi/s_lo ----
  {
    const int d = tid>>1, sh = tid&1, s0 = sh*8;
    float A_[8], wdt[8];
    {
      const float* ap = ws+OFF_ANEG + ((size_t)l*256+d)*16 + s0;
      const float* wp = ws+OFF_DTW + ((size_t)l*256+d)*8;
      #pragma unroll
      for (int j2=0;j2<8;j2++){ A_[j2]=ap[j2]; wdt[j2]=wp[j2]; }
    }
    const float Dv = ws[OFF_DD + l*256+d];
    const float bias = ws[OFF_DTPB + l*256+d];
    float h[8];
    #pragma unroll
    for (int ss=0;ss<8;ss++) h[ss]=0.f;
    for (int t=0;t<NP;t++){
      float4 q0 = *(const float4*)&s_dt[t*8], q1 = *(const float4*)&s_dt[t*8+4];
      float din = bias + q0.x*wdt[0]+q0.y*wdt[1]+q0.z*wdt[2]+q0.w*wdt[3]
                       + q1.x*wdt[4]+q1.y*wdt[5]+q1.z*wdt[6]+q1.w*wdt[7];
      float dtv = softplus(din);
      float xv = b2f(s_hi[t*264+d])+b2f(s_lo[t*264+d]);
      float dtx = dtv*xv;
      float4 B0=*(const float4*)&s_bc[t*32+s0],    B1=*(const float4*)&s_bc[t*32+s0+4];
      float4 C0=*(const float4*)&s_bc[t*32+16+s0], C1=*(const float4*)&s_bc[t*32+16+s0+4];
      float Bv[8]={B0.x,B0.y,B0.z,B0.w,B1.x,B1.y,B1.z,B1.w};
      float Cv[8]={C0.x,C0.y,C0.z,C0.w,C1.x,C1.y,C1.z,C1.w};
      float y = 0.f;
      #pragma unroll
      for (int ss=0;ss<8;ss++){
        float dA = __expf(dtv*A_[ss]);
        h[ss] = dA*h[ss] + dtx*Bv[ss];
        y += h[ss]*Cv[ss];
      }
      y += __shfl_xor(y,1,64);
      if (sh==0){
        float g0 = y + xv*Dv;
        us hh,lo2; split2(g0,hh,lo2);
        s_hi[t*264+d]=hh; s_lo[t*264+d]=lo2;
      }
    }
  }
  __syncthreads();

  // ---- phase 5: z-half GEMM (nt = 16+2w..) from p planes + gate in place ----
  {
    f32x4 acc[5][2];
    #pragma unroll
    for (int mt=0;mt<5;mt++){
      #pragma unroll
      for (int p=0;p<2;p++){ f32x4 z={0,0,0,0}; acc[mt][p]=z; }
    }
    #pragma unroll
    for (int kk=0;kk<4;kk++){
      bf16x8 B0 = *(const bf16x8*)&INF[((size_t)((16+2*w+0)*4+kk))*512 + lane*8];
      bf16x8 B1 = *(const bf16x8*)&INF[((size_t)((16+2*w+1)*4+kk))*512 + lane*8];
      #pragma unroll
      for (int mt=0;mt<5;mt++){
        int m = mt*16+ml; if (m>64) m=64;
        bf16x8 ah = *(const bf16x8*)&phi[(size_t)m*128 + kk*32 + quad*8];
        bf16x8 al = *(const bf16x8*)&plo[(size_t)m*128 + kk*32 + quad*8];
        acc[mt][0] = mfma16(ah,B0,mfma16(al,B0,acc[mt][0]));
        acc[mt][1] = mfma16(ah,B1,mfma16(al,B1,acc[mt][1]));
      }
    }
    #pragma unroll
    for (int p=0;p<2;p++){
      int d = (2*w+p)*16+ml;
      #pragma unroll
      for (int mt=0;mt<5;mt++)
        #pragma unroll
        for (int r=0;r<4;r++){
          int t = mt*16+quad*4+r;
          if (t<NP){
            float zv = acc[mt][p][r];
            float g0 = b2f(s_hi[t*264+d])+b2f(s_lo[t*264+d]);
            float g = g0 * zv * sigm(zv);
            us hh,lo2; split2(g,hh,lo2);
            s_hi[t*264+d]=hh; s_lo[t*264+d]=lo2;
          }
        }
    }
  }
  __syncthreads();

  // ---- phase 6: out_proj (nt = w), A = s_hi/s_lo -> pout planes ----
  {
    f32x4 acc[5];
    #pragma unroll
    for (int mt=0;mt<5;mt++){ f32x4 z={0,0,0,0}; acc[mt]=z; }
    #pragma unroll
    for (int kk=0;kk<8;kk++){
      bf16x8 B = *(const bf16x8*)&OPF[((size_t)(w*8+kk))*512 + lane*8];
      #pragma unroll
      for (int mt=0;mt<5;mt++){
        int row = mt*16+ml; if (row>64) row=64;
        bf16x8 ah = *(const bf16x8*)&s_hi[row*264 + kk*32 + quad*8];
        bf16x8 al = *(const bf16x8*)&s_lo[row*264 + kk*32 + quad*8];
        acc[mt] = mfma16(ah,B,mfma16(al,B,acc[mt]));
      }
    }
    int dm = w*16+ml;
    #pragma unroll
    for (int mt=0;mt<5;mt++)
      #pragma unroll
      for (int r=0;r<4;r++){
        int t = mt*16+quad*4+r;
        if (t<NP){
          us hh,lo2; split2(acc[mt][r],hh,lo2);
          pout[(size_t)n*HNF + t*128 + dm] = hh;
          pout[(size_t)n*HNF + t*128 + dm + LOPL] = lo2;
        }
      }
  }
}

// =====================================================================
// head GEMM (M=512,N=96,K=8320) from hi/lo planes + de-norm; 8-wave K-split
// =====================================================================
__global__ __launch_bounds__(512)
void k_head(const float* __restrict__ ws, void* __restrict__ out)
{
  const int blk = blockIdx.x;
  const int nt = blk%6, mt = blk/6;
  const int tid = threadIdx.x, w = tid>>6, lane = tid&63, ml = lane&15, quad = lane>>4;
  const us* pa_hi = (const us*)(ws+OFF_PA);
  const us* pa_lo = pa_hi + LOPL;
  const us* HDF = (const us*)(ws+OFF_HDF);
  __shared__ __align__(16) float red[8][64][4];

  const int base = w*32 + (w<4? w:4);
  const int cnt  = 32 + (w<4? 1:0);
  f32x4 acc={0,0,0,0};
  const size_t abase = (size_t)(mt*16+ml)*HNF + quad*8;
  for (int i=0;i<cnt;i++){
    int kk = base+i;
    bf16x8 ah = *(const bf16x8*)(pa_hi + abase + (size_t)kk*32);
    bf16x8 al = *(const bf16x8*)(pa_lo + abase + (size_t)kk*32);
    bf16x8 b = *(const bf16x8*)&HDF[((size_t)(nt*260+kk))*512 + lane*8];
    acc = mfma16(ah,b,mfma16(al,b,acc));
  }
  #pragma unroll
  for (int r=0;r<4;r++) red[w][lane][r]=acc[r];
  __syncthreads();
  if (w==0){
    const int isbf = ws[OFF_FLAG]!=0.f;
    #pragma unroll
    for (int r=0;r<4;r++){
      float s = 0.f;
      #pragma unroll
      for (int ww=0;ww<8;ww++) s += red[ww][lane][r];
      int nseq = mt*16 + quad*4 + r;
      int pred = nt*16 + ml;
      float val = s*ws[OFF_STD+nseq] + ws[OFF_MEAN+nseq];
      size_t o = ((size_t)(nseq>>4)*96 + pred)*16 + (nseq&15);
      if (isbf) ((us*)out)[o] = f2b(val);
      else      ((float*)out)[o] = val;
    }
  }
}

extern "C" void kernel_launch(void* const* d_in, const int* in_sizes, int n_in,
                              void* d_out, int out_size, void* d_ws, size_t ws_size,
                              hipStream_t stream)
{
  (void)in_sizes; (void)n_in; (void)out_size; (void)ws_size;
  float* ws = (float*)d_ws;
  const void* x_enc = d_in[0];
  const void* pe_w  = d_in[2];  const void* pe_b  = d_in[3];
  const void* in_w  = d_in[4];  const void* conv_w= d_in[5];
  const void* conv_b= d_in[6];  const void* xp_w  = d_in[7];
  const void* dtp_w = d_in[8];  const void* dtp_b = d_in[9];
  const void* A_log = d_in[10]; const void* Dm    = d_in[11];
  const void* op_w  = d_in[12]; const void* head_w= d_in[13];

  k_prep<<<569,256,0,stream>>>(x_enc,pe_w,pe_b,in_w,conv_w,conv_b,xp_w,dtp_w,
                               dtp_b,A_log,Dm,op_w,head_w,ws);
  k_embed<<<NSEQ,256,0,stream>>>(x_enc,ws);
  us* pa = (us*)(ws+OFF_PA);
  us* pb = (us*)(ws+OFF_PB);
  k_layer<<<NSEQ,512,0,stream>>>(0,pa,pb,ws);
  k_layer<<<NSEQ,512,0,stream>>>(1,pb,pa,ws);
  k_head<<<192,512,0,stream>>>(ws,d_out);
}

// Round 7
// 406.433 us; speedup vs baseline: 1.2409x; 1.0436x over previous
//
#include <hip/hip_runtime.h>

typedef __attribute__((ext_vector_type(8))) short bf16x8;
typedef __attribute__((ext_vector_type(4))) float f32x4;
typedef unsigned short us;

#define DEV static __device__ __forceinline__

// ---- config ----
constexpr int NP   = 65;      // NPATCH
constexpr int NSEQ = 512;     // B*C
constexpr int HNF  = 8320;    // DM*NP
constexpr int LOPL = NSEQ*HNF;   // shorts between hi and lo planes

// ---- ws layout (float offsets) ----
constexpr size_t OFF_FLAG = 0;
constexpr size_t OFF_MEAN = 16;        // 512
constexpr size_t OFF_STD  = 528;       // 512
constexpr size_t OFF_ANEG = 1040;      // 8192  (-exp(A_log)*log2e)
constexpr size_t OFF_CONVW= 9232;      // 2048
constexpr size_t OFF_CONVB= 11280;     // 512
constexpr size_t OFF_DTPB = 11792;     // 512
constexpr size_t OFF_DD   = 12304;     // 512
constexpr size_t OFF_PEWT = 12816;     // 2048
constexpr size_t OFF_PEB  = 14864;     // 128
constexpr size_t OFF_DTW  = 14992;     // 4096
constexpr size_t OFF_INF  = 19088;     // 131072 us = 65536 f
constexpr size_t OFF_XPF  = 84624;     // 24576 us = 12288 f
constexpr size_t OFF_OPF  = 96912;     // 65536 us = 32768 f
constexpr size_t OFF_HDF  = 129680;    // 798720 us = 399360 f
constexpr size_t OFF_PA   = 529040;    // hi+lo planes: 2*NSEQ*HNF shorts
constexpr size_t OFF_PB   = OFF_PA + (size_t)NSEQ*HNF;

// per-layer strides in us elements
constexpr size_t STR_INF = 65536;   // 32 nt * 4 kk * 512
constexpr size_t STR_XPF = 12288;   // 3 nt * 8 kk * 512
constexpr size_t STR_OPF = 32768;   // 8 nt * 8 kk * 512

DEV float b2f(us u){ union{unsigned v; float f;} x; x.v = ((unsigned)u)<<16; return x.f; }
DEV us f2b(float f){
  union{float f32; unsigned u;} x; x.f32 = f;
  unsigned r = x.u + 0x7fffu + ((x.u>>16)&1u);
  return (us)(r>>16);
}
DEV void split2(float v, us& h, us& l){ h = f2b(v); l = f2b(v - b2f(h)); }
DEV float load_in(const void* p, size_t i, int isbf){
  return isbf ? b2f(((const us*)p)[i]) : ((const float*)p)[i];
}
DEV int detect_bf16(const void* x){
  const us* u = (const us*)x;
  int sane = 0;
  for (int i=0;i<128;i++){
    us v = u[2*i];
    int e = (v>>7)&0xff;
    if (v==0 || (e>=100 && e<=141)) sane++;
  }
  return sane >= 96;
}
DEV f32x4 mfma16(bf16x8 a, bf16x8 b, f32x4 c){
  return __builtin_amdgcn_mfma_f32_16x16x32_bf16(a,b,c,0,0,0);
}
DEV float sigm(float x){ return 1.f/(1.f+__expf(-x)); }
DEV float softplus(float x){ return fmaxf(x,0.f)+__logf(1.f+__expf(-fabsf(x))); }

// =====================================================================
// prep
// =====================================================================
__global__ void k_prep(const void* x_enc, const void* pe_w, const void* pe_b,
                       const void* in_w, const void* conv_w, const void* conv_b,
                       const void* xp_w, const void* dtp_w, const void* dtp_b,
                       const void* A_log, const void* Dm, const void* op_w,
                       const void* head_w, float* __restrict__ ws)
{
  __shared__ int sflag;
  if (threadIdx.x==0) sflag = detect_bf16(x_enc);
  __syncthreads();
  const int isbf = sflag;
  if (blockIdx.x==0 && threadIdx.x==0) ws[OFF_FLAG] = (float)isbf;

  size_t i = (size_t)blockIdx.x*256 + threadIdx.x;
  if (i < 8192){ ws[OFF_ANEG+i] = -__expf(load_in(A_log,i,isbf))*1.44269504f; return; } i -= 8192;
  if (i < 2048){ ws[OFF_CONVW+i] = load_in(conv_w,i,isbf); return; } i -= 2048;
  if (i < 512){ ws[OFF_CONVB+i] = load_in(conv_b,i,isbf); return; } i -= 512;
  if (i < 512){ ws[OFF_DTPB+i]  = load_in(dtp_b,i,isbf); return; } i -= 512;
  if (i < 512){ ws[OFF_DD+i]    = load_in(Dm,i,isbf); return; } i -= 512;
  if (i < 2048){ size_t k=i>>7, dm=i&127; ws[OFF_PEWT+i]=load_in(pe_w, dm*16+k, isbf); return; } i -= 2048;
  if (i < 128){ ws[OFF_PEB+i]   = load_in(pe_b,i,isbf); return; } i -= 128;
  if (i < 4096){ ws[OFF_DTW+i]  = load_in(dtp_w,i,isbf); return; } i -= 4096;
  if (i < 16384){ // INF: [l][nt32][kk4][lane][8]; B[k=d(128)][e(512)]=in_w[e][k]
    size_t lane=i&63, tile=i>>6;
    size_t kk=tile&3, nt=(tile>>2)&31, l=tile>>7;
    size_t e=nt*16+(lane&15), k0=kk*32+((lane>>4)*8);
    bf16x8 v;
    #pragma unroll
    for (int j=0;j<8;j++) v[j]=(short)f2b(load_in(in_w,(l*512+e)*128+k0+j,isbf));
    *(bf16x8*)&((us*)(ws+OFF_INF))[i*8] = v; return;
  } i -= 16384;
  if (i < 3072){ // XPF: [l][nt3][kk8]; B[k=d(256)][o(48 pad)]=xp_w[o][k]
    size_t lane=i&63, tile=i>>6;
    size_t kk=tile&7, rest=tile>>3, nt=rest%3, l=rest/3;
    size_t o=nt*16+(lane&15), k0=kk*32+((lane>>4)*8);
    bf16x8 v;
    #pragma unroll
    for (int j=0;j<8;j++) v[j]=(short)((o<40)? f2b(load_in(xp_w,(l*40+o)*256+k0+j,isbf)) : 0);
    *(bf16x8*)&((us*)(ws+OFF_XPF))[i*8] = v; return;
  } i -= 3072;
  if (i < 8192){ // OPF: [l][nt8][kk8]; B[k=d(256)][dm(128)]=op_w[dm][k]
    size_t lane=i&63, tile=i>>6;
    size_t kk=tile&7, nt=(tile>>3)&7, l=tile>>6;
    size_t dm=nt*16+(lane&15), k0=kk*32+((lane>>4)*8);
    bf16x8 v;
    #pragma unroll
    for (int j=0;j<8;j++) v[j]=(short)f2b(load_in(op_w,(l*128+dm)*256+k0+j,isbf));
    *(bf16x8*)&((us*)(ws+OFF_OPF))[i*8] = v; return;
  } i -= 8192;
  if (i < 99840){ // HDF: [nt6][kk260]; B[k(8320)][pred(96)]=head_w[pred][k]
    size_t lane=i&63, tile=i>>6;
    size_t kk=tile%260, nt=tile/260;
    size_t pr=nt*16+(lane&15), k0=kk*32+((lane>>4)*8);
    bf16x8 v;
    #pragma unroll
    for (int j=0;j<8;j++) v[j]=(short)f2b(load_in(head_w,pr*8320+k0+j,isbf));
    *(bf16x8*)&((us*)(ws+OFF_HDF))[i*8] = v; return;
  }
}

// =====================================================================
// RevIN + patch-embed -> PA (hi/lo bf16 planes)
// =====================================================================
__global__ void k_embed(const void* __restrict__ x_enc, float* __restrict__ ws)
{
  const int n = blockIdx.x, tid = threadIdx.x;
  const int b = n>>4, c = n&15;
  const int isbf = ws[OFF_FLAG] != 0.f;
  __shared__ __align__(16) float sx[512];
  __shared__ __align__(16) float spe[16*128];
  __shared__ __align__(16) float spb[128];
  __shared__ float rs[4], rq[4], sm[2];

  float v0 = load_in(x_enc, ((size_t)b*512+tid)*16 + c, isbf);
  float v1 = load_in(x_enc, ((size_t)b*512+tid+256)*16 + c, isbf);
  float s = v0+v1, q = v0*v0+v1*v1;
  for (int o=32;o;o>>=1){ s += __shfl_down(s,o,64); q += __shfl_down(q,o,64); }
  const int w = tid>>6, lane = tid&63;
  if (lane==0){ rs[w]=s; rq[w]=q; }
  __syncthreads();
  if (tid==0){
    float S=rs[0]+rs[1]+rs[2]+rs[3], Q=rq[0]+rq[1]+rq[2]+rq[3];
    float mean = S*(1.f/512.f);
    float var = fmaxf(Q*(1.f/512.f)-mean*mean, 0.f);
    float sd = sqrtf(var+1e-5f);
    sm[0]=mean; sm[1]=1.f/sd;
    ws[OFF_MEAN+n]=mean; ws[OFF_STD+n]=sd;
  }
  __syncthreads();
  const float mean=sm[0], rstd=sm[1];
  sx[tid]=(v0-mean)*rstd; sx[tid+256]=(v1-mean)*rstd;
  for (int i=tid;i<2048;i+=256) spe[i]=ws[OFF_PEWT+i];
  if (tid<128) spb[tid]=ws[OFF_PEB+tid];
  __syncthreads();

  us* pa_hi = (us*)(ws+OFF_PA);
  us* pa_lo = pa_hi + LOPL;
  for (int i=tid;i<NP*128;i+=256){
    int t=i>>7, dm=i&127;
    float acc = spb[dm];
    int j0 = t*8-8;
    #pragma unroll
    for (int k=0;k<16;k++){ int j=j0+k; if ((unsigned)j<512u) acc += sx[j]*spe[k*128+dm]; }
    us h,lo2; split2(acc,h,lo2);
    pa_hi[(size_t)n*HNF+i] = h;
    pa_lo[(size_t)n*HNF+i] = lo2;
  }
}

// =====================================================================
// Fused Mamba layer: 512 threads, 79040 B LDS, 2 blocks/CU (16 waves/CU)
// =====================================================================
__global__ __launch_bounds__(512,2)
void k_layer(int l, const us* __restrict__ pin, us* __restrict__ pout,
             float* __restrict__ ws)
{
  const int n = blockIdx.x, tid = threadIdx.x;
  const int w = tid>>6, lane = tid&63, ml = lane&15, quad = lane>>4;

  // LDS: s_hi[65][264] bf16 | s_lo[65][264] bf16 | s_dt[65][8] f32 | s_bc[65][32] f32
  __shared__ __align__(16) unsigned char arena[79040];
  us* s_hi = (us*)arena;
  us* s_lo = (us*)(arena+34320);
  float* s_dt = (float*)(arena+68640);
  float* s_bc = (float*)(arena+70720);

  const us* INF = (const us*)(ws+OFF_INF) + (size_t)l*STR_INF;
  const us* XPF = (const us*)(ws+OFF_XPF) + (size_t)l*STR_XPF;
  const us* OPF = (const us*)(ws+OFF_OPF) + (size_t)l*STR_OPF;
  const us* phi = pin + (size_t)n*HNF;
  const us* plo = phi + LOPL;

  // ---- phase 1: in_proj xin-half (nt = 2w, 2w+1) ----
  {
    f32x4 acc[5][2];
    #pragma unroll
    for (int mt=0;mt<5;mt++){
      #pragma unroll
      for (int p=0;p<2;p++){ f32x4 z={0,0,0,0}; acc[mt][p]=z; }
    }
    #pragma unroll
    for (int kk=0;kk<4;kk++){
      bf16x8 B0 = *(const bf16x8*)&INF[((size_t)((2*w+0)*4+kk))*512 + lane*8];
      bf16x8 B1 = *(const bf16x8*)&INF[((size_t)((2*w+1)*4+kk))*512 + lane*8];
      #pragma unroll
      for (int mt=0;mt<5;mt++){
        int m = mt*16+ml; if (m>64) m=64;
        bf16x8 ah = *(const bf16x8*)&phi[(size_t)m*128 + kk*32 + quad*8];
        bf16x8 al = *(const bf16x8*)&plo[(size_t)m*128 + kk*32 + quad*8];
        acc[mt][0] = mfma16(ah,B0,mfma16(al,B0,acc[mt][0]));
        acc[mt][1] = mfma16(ah,B1,mfma16(al,B1,acc[mt][1]));
      }
    }
    #pragma unroll
    for (int p=0;p<2;p++){
      int e = (2*w+p)*16+ml;
      #pragma unroll
      for (int mt=0;mt<4;mt++)
        #pragma unroll
        for (int r=0;r<4;r++){
          int t = mt*16+quad*4+r;
          us h,lo2; split2(acc[mt][p][r],h,lo2);
          s_hi[t*264+e]=h; s_lo[t*264+e]=lo2;
        }
      if (quad==0){
        us h,lo2; split2(acc[4][p][0],h,lo2);
        s_hi[64*264+e]=h; s_lo[64*264+e]=lo2;
      }
    }
  }
  __syncthreads();

  // ---- phase 2: causal conv(4)+SiLU in place, t-split halves ----
  {
    const int d = tid&255, half = tid>>8;
    float x0=0.f,x1=0.f,x2=0.f;
    if (half){
      x0 = b2f(s_hi[30*264+d])+b2f(s_lo[30*264+d]);
      x1 = b2f(s_hi[31*264+d])+b2f(s_lo[31*264+d]);
      x2 = b2f(s_hi[32*264+d])+b2f(s_lo[32*264+d]);
    }
    __syncthreads();
    const float4 wv = ((const float4*)(ws+OFF_CONVW))[l*256+d];
    const float bb = ws[OFF_CONVB + l*256+d];
    const int t0 = half?33:0, tn = half?NP:33;
    for (int t=t0;t<tn;t++){
      float xi = b2f(s_hi[t*264+d])+b2f(s_lo[t*264+d]);
      float v = bb + wv.x*x0 + wv.y*x1 + wv.z*x2 + wv.w*xi;
      x0=x1; x1=x2; x2=xi;
      float sv = v * sigm(v);
      us h,lo2; split2(sv,h,lo2);
      s_hi[t*264+d]=h; s_lo[t*264+d]=lo2;
    }
  }
  __syncthreads();

  // ---- phase 3: x_proj (15 tiles / 8 waves) ----
  {
    for (int ti=w; ti<15; ti+=8){
      int mt=ti/3, nt=ti%3;
      int row = mt*16+ml; if (row>64) row=64;
      f32x4 acc={0,0,0,0};
      #pragma unroll
      for (int kk=0;kk<8;kk++){
        bf16x8 ah = *(const bf16x8*)&s_hi[row*264 + kk*32 + quad*8];
        bf16x8 al = *(const bf16x8*)&s_lo[row*264 + kk*32 + quad*8];
        bf16x8 b  = *(const bf16x8*)&XPF[((size_t)(nt*8+kk))*512 + lane*8];
        acc = mfma16(ah,b,mfma16(al,b,acc));
      }
      #pragma unroll
      for (int r=0;r<4;r++){
        int t = mt*16+quad*4+r;
        bool tok = (mt<4) || (quad==0 && r==0);
        if (tok){
          if (nt==0){
            if (ml<8) s_dt[t*8+ml] = acc[r];
            else      s_bc[t*32+(ml-8)] = acc[r];
          } else if (nt==1){
            s_bc[t*32+8+ml] = acc[r];
          } else {
            if (ml<8) s_bc[t*32+24+ml] = acc[r];
          }
        }
      }
    }
  }
  __syncthreads();

  // ---- phase 4: scan, thread=(d, s-half of 8 states); g0 -> s_hi/s_lo ----
  {
    const int d = tid>>1, sh = tid&1, s0 = sh*8;
    float A_[8], wdt[8];
    {
      const float* ap = ws+OFF_ANEG + ((size_t)l*256+d)*16 + s0;
      const float* wp = ws+OFF_DTW + ((size_t)l*256+d)*8;
      #pragma unroll
      for (int j2=0;j2<8;j2++){ A_[j2]=ap[j2]; wdt[j2]=wp[j2]; }
    }
    const float Dv = ws[OFF_DD + l*256+d];
    const float bias = ws[OFF_DTPB + l*256+d];
    float h[8];
    #pragma unroll
    for (int ss=0;ss<8;ss++) h[ss]=0.f;
    for (int t=0;t<NP;t++){
      float4 q0 = *(const float4*)&s_dt[t*8], q1 = *(const float4*)&s_dt[t*8+4];
      float din = bias + q0.x*wdt[0]+q0.y*wdt[1]+q0.z*wdt[2]+q0.w*wdt[3]
                       + q1.x*wdt[4]+q1.y*wdt[5]+q1.z*wdt[6]+q1.w*wdt[7];
      float dtv = softplus(din);
      float xv = b2f(s_hi[t*264+d])+b2f(s_lo[t*264+d]);
      float dtx = dtv*xv;
      float4 B0=*(const float4*)&s_bc[t*32+s0],    B1=*(const float4*)&s_bc[t*32+s0+4];
      float4 C0=*(const float4*)&s_bc[t*32+16+s0], C1=*(const float4*)&s_bc[t*32+16+s0+4];
      float Bv[8]={B0.x,B0.y,B0.z,B0.w,B1.x,B1.y,B1.z,B1.w};
      float Cv[8]={C0.x,C0.y,C0.z,C0.w,C1.x,C1.y,C1.z,C1.w};
      float y = 0.f;
      #pragma unroll
      for (int ss=0;ss<8;ss++){
        float dA = exp2f(dtv*A_[ss]);   // A pre-scaled by log2e
        h[ss] = dA*h[ss] + dtx*Bv[ss];
        y += h[ss]*Cv[ss];
      }
      y += __shfl_xor(y,1,64);
      if (sh==0){
        float g0 = y + xv*Dv;
        us hh,lo2; split2(g0,hh,lo2);
        s_hi[t*264+d]=hh; s_lo[t*264+d]=lo2;
      }
    }
  }
  __syncthreads();

  // ---- phase 5: z-half GEMM (nt = 16+2w..) + gate in place ----
  {
    f32x4 acc[5][2];
    #pragma unroll
    for (int mt=0;mt<5;mt++){
      #pragma unroll
      for (int p=0;p<2;p++){ f32x4 z={0,0,0,0}; acc[mt][p]=z; }
    }
    #pragma unroll
    for (int kk=0;kk<4;kk++){
      bf16x8 B0 = *(const bf16x8*)&INF[((size_t)((16+2*w+0)*4+kk))*512 + lane*8];
      bf16x8 B1 = *(const bf16x8*)&INF[((size_t)((16+2*w+1)*4+kk))*512 + lane*8];
      #pragma unroll
      for (int mt=0;mt<5;mt++){
        int m = mt*16+ml; if (m>64) m=64;
        bf16x8 ah = *(const bf16x8*)&phi[(size_t)m*128 + kk*32 + quad*8];
        bf16x8 al = *(const bf16x8*)&plo[(size_t)m*128 + kk*32 + quad*8];
        acc[mt][0] = mfma16(ah,B0,mfma16(al,B0,acc[mt][0]));
        acc[mt][1] = mfma16(ah,B1,mfma16(al,B1,acc[mt][1]));
      }
    }
    #pragma unroll
    for (int p=0;p<2;p++){
      int d = (2*w+p)*16+ml;
      #pragma unroll
      for (int mt=0;mt<4;mt++)
        #pragma unroll
        for (int r=0;r<4;r++){
          int t = mt*16+quad*4+r;
          float zv = acc[mt][p][r];
          float g0 = b2f(s_hi[t*264+d])+b2f(s_lo[t*264+d]);
          float g = g0 * zv * sigm(zv);
          us hh,lo2; split2(g,hh,lo2);
          s_hi[t*264+d]=hh; s_lo[t*264+d]=lo2;
        }
      if (quad==0){
        float zv = acc[4][p][0];
        float g0 = b2f(s_hi[64*264+d])+b2f(s_lo[64*264+d]);
        float g = g0 * zv * sigm(zv);
        us hh,lo2; split2(g,hh,lo2);
        s_hi[64*264+d]=hh; s_lo[64*264+d]=lo2;
      }
    }
  }
  __syncthreads();

  // ---- phase 6: out_proj (nt = w) -> pout planes ----
  {
    f32x4 acc[5];
    #pragma unroll
    for (int mt=0;mt<5;mt++){ f32x4 z={0,0,0,0}; acc[mt]=z; }
    #pragma unroll
    for (int kk=0;kk<8;kk++){
      bf16x8 B = *(const bf16x8*)&OPF[((size_t)(w*8+kk))*512 + lane*8];
      #pragma unroll
      for (int mt=0;mt<5;mt++){
        int row = mt*16+ml; if (row>64) row=64;
        bf16x8 ah = *(const bf16x8*)&s_hi[row*264 + kk*32 + quad*8];
        bf16x8 al = *(const bf16x8*)&s_lo[row*264 + kk*32 + quad*8];
        acc[mt] = mfma16(ah,B,mfma16(al,B,acc[mt]));
      }
    }
    int dm = w*16+ml;
    #pragma unroll
    for (int mt=0;mt<4;mt++)
      #pragma unroll
      for (int r=0;r<4;r++){
        int t = mt*16+quad*4+r;
        us hh,lo2; split2(acc[mt][r],hh,lo2);
        pout[(size_t)n*HNF + t*128 + dm] = hh;
        pout[(size_t)n*HNF + t*128 + dm + LOPL] = lo2;
      }
    if (quad==0){
      us hh,lo2; split2(acc[4][0],hh,lo2);
      pout[(size_t)n*HNF + 64*128 + dm] = hh;
      pout[(size_t)n*HNF + 64*128 + dm + LOPL] = lo2;
    }
  }
}

// =====================================================================
// head GEMM (M=512,N=96,K=8320) + de-norm; 8-wave K-split, pipelined loads
// =====================================================================
__global__ __launch_bounds__(512,1)
void k_head(const float* __restrict__ ws, void* __restrict__ out)
{
  const int blk = blockIdx.x;
  const int nt = blk%6, mt = blk/6;
  const int tid = threadIdx.x, w = tid>>6, lane = tid&63, ml = lane&15, quad = lane>>4;
  const us* pa_hi = (const us*)(ws+OFF_PA);
  const us* pa_lo = pa_hi + LOPL;
  const us* HDF = (const us*)(ws+OFF_HDF);
  __shared__ __align__(16) float red[8][64][4];

  const int base = w*32 + (w<4? w:4);
  const int cnt  = 32 + (w<4? 1:0);
  f32x4 acc={0,0,0,0};
  const size_t abase = (size_t)(mt*16+ml)*HNF + quad*8;

  bf16x8 ah = *(const bf16x8*)(pa_hi + abase + (size_t)base*32);
  bf16x8 al = *(const bf16x8*)(pa_lo + abase + (size_t)base*32);
  bf16x8 b  = *(const bf16x8*)&HDF[((size_t)(nt*260+base))*512 + lane*8];
  for (int i=1;i<cnt;i++){
    int kk = base+i;
    bf16x8 ah2 = *(const bf16x8*)(pa_hi + abase + (size_t)kk*32);
    bf16x8 al2 = *(const bf16x8*)(pa_lo + abase + (size_t)kk*32);
    bf16x8 b2  = *(const bf16x8*)&HDF[((size_t)(nt*260+kk))*512 + lane*8];
    acc = mfma16(ah,b,mfma16(al,b,acc));
    ah=ah2; al=al2; b=b2;
  }
  acc = mfma16(ah,b,mfma16(al,b,acc));

  #pragma unroll
  for (int r=0;r<4;r++) red[w][lane][r]=acc[r];
  __syncthreads();
  if (w==0){
    const int isbf = ws[OFF_FLAG]!=0.f;
    #pragma unroll
    for (int r=0;r<4;r++){
      float s = 0.f;
      #pragma unroll
      for (int ww=0;ww<8;ww++) s += red[ww][lane][r];
      int nseq = mt*16 + quad*4 + r;
      int pred = nt*16 + ml;
      float val = s*ws[OFF_STD+nseq] + ws[OFF_MEAN+nseq];
      size_t o = ((size_t)(nseq>>4)*96 + pred)*16 + (nseq&15);
      if (isbf) ((us*)out)[o] = f2b(val);
      else      ((float*)out)[o] = val;
    }
  }
}

extern "C" void kernel_launch(void* const* d_in, const int* in_sizes, int n_in,
                              void* d_out, int out_size, void* d_ws, size_t ws_size,
                              hipStream_t stream)
{
  (void)in_sizes; (void)n_in; (void)out_size; (void)ws_size;
  float* ws = (float*)d_ws;
  const void* x_enc = d_in[0];
  const void* pe_w  = d_in[2];  const void* pe_b  = d_in[3];
  const void* in_w  = d_in[4];  const void* conv_w= d_in[5];
  const void* conv_b= d_in[6];  const void* xp_w  = d_in[7];
  const void* dtp_w = d_in[8];  const void* dtp_b = d_in[9];
  const void* A_log = d_in[10]; const void* Dm    = d_in[11];
  const void* op_w  = d_in[12]; const void* head_w= d_in[13];

  k_prep<<<569,256,0,stream>>>(x_enc,pe_w,pe_b,in_w,conv_w,conv_b,xp_w,dtp_w,
                               dtp_b,A_log,Dm,op_w,head_w,ws);
  k_embed<<<NSEQ,256,0,stream>>>(x_enc,ws);
  us* pa = (us*)(ws+OFF_PA);
  us* pb = (us*)(ws+OFF_PB);
  k_layer<<<NSEQ,512,0,stream>>>(0,pa,pb,ws);
  k_layer<<<NSEQ,512,0,stream>>>(1,pb,pa,ws);
  k_head<<<192,512,0,stream>>>(ws,d_out);
}